// Round 3
// baseline (177.463 us; speedup 1.0000x reference)
//
#include <hip/hip_runtime.h>
#include <math.h>

// BalancedL1Loss fused reduction.
// Key identity: weight depends only on bin index, so
//   loss = (sum_b wi[b]*S_b + S_inv) / (sum_b wi[b]*N_b + N_inv)
// with S_b = sum of |o-t| over elements in bin b, N_b = count in bin b.
// One pass over outputs+targets (134 MB) -> 17 (S,N) pairs -> tiny finalize.

#define NBIN 16
#define NSLOT 17            // slot 0 = invalid (t < bins[0]); slot j = bin j-1
#define THREADS 256
#define NBLOCKS 1024

// ws layout: ws[0..16] = S (slot-major), ws[17..33] = N

__global__ __launch_bounds__(THREADS, 4)
void bll_hist(const float* __restrict__ outputs, const float* __restrict__ targets,
              float* __restrict__ ws, int n4) {
    // Per-thread privatized histograms: no atomics, no contention.
    __shared__ float S_lds[THREADS * NSLOT];   // 17.4 KB
    __shared__ float N_lds[THREADS * NSLOT];   // 17.4 KB
    const int tid = threadIdx.x;
    const int base = tid * NSLOT;

    #pragma unroll
    for (int s = 0; s < NSLOT; ++s) {
        S_lds[base + s] = 0.0f;
        N_lds[base + s] = 0.0f;
    }
    // No barrier needed: each thread touches only its own 17-slot row until
    // the reduction phase below.

    // float32 values of np.arange(0.2, 1.0, 0.05) after f64->f32 cast.
    const float bins[NBIN] = {0.20f, 0.25f, 0.30f, 0.35f, 0.40f, 0.45f, 0.50f, 0.55f,
                              0.60f, 0.65f, 0.70f, 0.75f, 0.80f, 0.85f, 0.90f, 0.95f};

    const float4* __restrict__ t4p = (const float4*)targets;
    const float4* __restrict__ o4p = (const float4*)outputs;
    const int stride = gridDim.x * THREADS;

    for (int i = blockIdx.x * THREADS + tid; i < n4; i += stride) {
        const float4 t = t4p[i];
        const float4 o = o4p[i];
        const float tv[4] = {t.x, t.y, t.z, t.w};
        const float ov[4] = {o.x, o.y, o.z, o.w};
        #pragma unroll
        for (int c = 0; c < 4; ++c) {
            const float tc = tv[c];
            // k = #(bins[b] <= tc) in [0,16]; exact searchsorted(side='right').
            int k = 0;
            #pragma unroll
            for (int b = 0; b < NBIN; ++b) k += (tc >= bins[b]) ? 1 : 0;
            const float l1 = fabsf(ov[c] - tc);
            const int sl = base + k;
            S_lds[sl] += l1;
            N_lds[sl] += 1.0f;
        }
    }
    __syncthreads();

    // Tree-reduce 256 private rows -> row 0. Stride 17 (odd) => conflict-friendly.
    for (int off = THREADS / 2; off > 0; off >>= 1) {
        if (tid < off) {
            #pragma unroll
            for (int s = 0; s < NSLOT; ++s) {
                S_lds[tid * NSLOT + s] += S_lds[(tid + off) * NSLOT + s];
                N_lds[tid * NSLOT + s] += N_lds[(tid + off) * NSLOT + s];
            }
        }
        __syncthreads();
    }

    if (tid < NSLOT) {
        unsafeAtomicAdd(&ws[tid], S_lds[tid]);               // S slots
    } else if (tid < 2 * NSLOT) {
        unsafeAtomicAdd(&ws[tid], N_lds[tid - NSLOT]);       // N slots
    }
}

__global__ void bll_final(const float* __restrict__ ws, const float* __restrict__ counts,
                          float* __restrict__ out) {
    if (threadIdx.x == 0 && blockIdx.x == 0) {
        const float S_inv = ws[0];
        const float N_inv = ws[NSLOT];     // ws[17]
        float newc[NBIN];
        float total = 0.0f;
        #pragma unroll
        for (int b = 0; b < NBIN; ++b) {
            newc[b] = 0.9f * counts[b] + 0.1f * ws[NSLOT + 1 + b];   // N_b at ws[18+b]
            total += newc[b];
        }
        float num = S_inv;
        float den = N_inv;
        #pragma unroll
        for (int b = 0; b < NBIN; ++b) {
            const float wi = sqrtf(total / newc[b]);   // (REPEAT_THR/freq)^GAMMA, GAMMA=0.5
            num += wi * ws[1 + b];                     // S_b
            den += wi * ws[NSLOT + 1 + b];             // N_b
        }
        out[0] = num / den;                            // * LOSS_WEIGHT (=1)
    }
}

extern "C" void kernel_launch(void* const* d_in, const int* in_sizes, int n_in,
                              void* d_out, int out_size, void* d_ws, size_t ws_size,
                              hipStream_t stream) {
    const float* outputs = (const float*)d_in[0];
    const float* targets = (const float*)d_in[1];
    const float* counts  = (const float*)d_in[2];
    float* out = (float*)d_out;
    float* ws  = (float*)d_ws;

    const int n  = in_sizes[0];   // 64*512*512 = 16,777,216 (divisible by 4)
    const int n4 = n >> 2;

    hipMemsetAsync(ws, 0, 2 * NSLOT * sizeof(float), stream);
    bll_hist<<<NBLOCKS, THREADS, 0, stream>>>(outputs, targets, ws, n4);
    bll_final<<<1, 64, 0, stream>>>(ws, counts, out);
}

// Round 6
// 166.139 us; speedup vs baseline: 1.0682x; 1.0682x over previous
//
#include <hip/hip_runtime.h>
#include <math.h>

// BalancedL1Loss — cumulative register-histogram formulation.
//
// weight depends only on bin index =>
//   loss = (sum_b wi[b]*S_b + S_inv) / (sum_b wi[b]*N_b + N_inv)
// Instead of scattering into a 17-slot histogram (LDS rmw: bank conflicts +
// occupancy cap + latency-bound, measured 66us @12% HBM), accumulate
// CUMULATIVE sums in registers:
//   cumS[b] = sum l1 * [t >= bins[b]],  cumN[b] = count [t >= bins[b]]
// Per-bin sums are adjacent differences; slot_inv from totals. All indices
// compile-time => pure VGPR, zero LDS in the hot loop. Counts ride the SALU
// pipe via ballot+popcount.

#define NBIN 16
#define THREADS 256
#define NBLOCKS 2048
#define WS_STRIDE 64   // spread the 33 global accumulators 256B apart (distinct L2 lines)

__global__ __launch_bounds__(THREADS)
void bll_pass(const float* __restrict__ outputs, const float* __restrict__ targets,
              float* __restrict__ ws, int n4) {
    // float32 values of np.arange(0.2, 1.0, 0.05) after f64->f32 cast.
    const float bins[NBIN] = {0.20f, 0.25f, 0.30f, 0.35f, 0.40f, 0.45f, 0.50f, 0.55f,
                              0.60f, 0.65f, 0.70f, 0.75f, 0.80f, 0.85f, 0.90f, 0.95f};

    float cs[NBIN];            // cumulative weighted-L1 sums (per-lane, VGPR)
    int   cn[NBIN];            // cumulative counts (wave-uniform via ballot, SGPR)
    float ts = 0.0f;           // total L1 sum
    #pragma unroll
    for (int b = 0; b < NBIN; ++b) { cs[b] = 0.0f; cn[b] = 0; }

    const float4* __restrict__ t4p = (const float4*)targets;
    const float4* __restrict__ o4p = (const float4*)outputs;
    const int stride = gridDim.x * THREADS;

    for (int i = blockIdx.x * THREADS + threadIdx.x; i < n4; i += stride) {
        const float4 t = t4p[i];
        const float4 o = o4p[i];
        const float tv[4] = {t.x, t.y, t.z, t.w};
        const float ov[4] = {o.x, o.y, o.z, o.w};
        #pragma unroll
        for (int c = 0; c < 4; ++c) {
            const float tc = tv[c];
            const float l1 = fabsf(ov[c] - tc);
            ts += l1;
            #pragma unroll
            for (int b = 0; b < NBIN; ++b) {
                const bool p = (tc >= bins[b]);          // exact searchsorted predicate
                cs[b] += p ? l1 : 0.0f;                  // v_cmp + v_cndmask + v_add
                cn[b] += (int)__popcll(__ballot(p));     // SALU: s_bcnt1 + s_add (wave-uniform)
            }
        }
    }

    // ---- reduction: wave butterfly (cs, ts); cn is already the wave sum ----
    #pragma unroll
    for (int b = 0; b < NBIN; ++b) {
        #pragma unroll
        for (int off = 32; off; off >>= 1) cs[b] += __shfl_xor(cs[b], off);
    }
    #pragma unroll
    for (int off = 32; off; off >>= 1) ts += __shfl_xor(ts, off);

    __shared__ float red[4][33];   // 4 waves x (16 cs + 16 cn + ts)
    const int lane = threadIdx.x & 63;
    const int wv   = threadIdx.x >> 6;
    if (lane == 0) {
        #pragma unroll
        for (int b = 0; b < NBIN; ++b) {
            red[wv][b]        = cs[b];
            red[wv][NBIN + b] = (float)cn[b];
        }
        red[wv][32] = ts;
    }
    __syncthreads();
    if (threadIdx.x < 33) {
        const float v = red[0][threadIdx.x] + red[1][threadIdx.x] +
                        red[2][threadIdx.x] + red[3][threadIdx.x];
        unsafeAtomicAdd(&ws[threadIdx.x * WS_STRIDE], v);
    }
}

// ws[s*WS_STRIDE]: s in [0,16) = cumS, [16,32) = cumN, 32 = totS
__global__ void bll_final(const float* __restrict__ ws, const float* __restrict__ counts,
                          float* __restrict__ out, float totN) {
    if (threadIdx.x == 0 && blockIdx.x == 0) {
        float cumS[NBIN + 1], cumN[NBIN + 1];
        #pragma unroll
        for (int b = 0; b < NBIN; ++b) {
            cumS[b] = ws[b * WS_STRIDE];
            cumN[b] = ws[(NBIN + b) * WS_STRIDE];
        }
        cumS[NBIN] = 0.0f;
        cumN[NBIN] = 0.0f;
        const float totS = ws[32 * WS_STRIDE];

        const float S_inv = totS - cumS[0];
        const float N_inv = totN - cumN[0];

        float Nb[NBIN], Sb[NBIN], newc[NBIN];
        float total = 0.0f;
        #pragma unroll
        for (int b = 0; b < NBIN; ++b) {
            Sb[b] = cumS[b] - cumS[b + 1];
            Nb[b] = cumN[b] - cumN[b + 1];
            newc[b] = 0.9f * counts[b] + 0.1f * Nb[b];   // EMA
            total += newc[b];
        }
        float num = S_inv;
        float den = N_inv;
        #pragma unroll
        for (int b = 0; b < NBIN; ++b) {
            const float wi = sqrtf(total / newc[b]);     // (1/freq)^0.5
            num += wi * Sb[b];
            den += wi * Nb[b];
        }
        out[0] = num / den;                              // * LOSS_WEIGHT (=1)
    }
}

extern "C" void kernel_launch(void* const* d_in, const int* in_sizes, int n_in,
                              void* d_out, int out_size, void* d_ws, size_t ws_size,
                              hipStream_t stream) {
    const float* outputs = (const float*)d_in[0];
    const float* targets = (const float*)d_in[1];
    const float* counts  = (const float*)d_in[2];
    float* out = (float*)d_out;
    float* ws  = (float*)d_ws;

    const int n  = in_sizes[0];   // 64*512*512 = 16,777,216 (divisible by 4)
    const int n4 = n >> 2;

    hipMemsetAsync(ws, 0, 33 * WS_STRIDE * sizeof(float), stream);
    bll_pass<<<NBLOCKS, THREADS, 0, stream>>>(outputs, targets, ws, n4);
    bll_final<<<1, 64, 0, stream>>>(ws, counts, out, (float)n);
}

// Round 11
// 157.863 us; speedup vs baseline: 1.1242x; 1.0524x over previous
//
#include <hip/hip_runtime.h>
#include <math.h>

// BalancedL1Loss — cumulative register-histogram, v2.
//
// loss = (sum_b wi[b]*S_b + S_inv) / (sum_b wi[b]*N_b + N_inv); weight is a
// pure function of bin index. Accumulate CUMULATIVE sums in registers:
//   cs[b] = sum l1*[t>=bins[b]],  cn[b] = #[t>=bins[b]]  (exact searchsorted)
// Round-6 evidence: dur 68us @ VALUBusy 33%, HBM 12% -> loop not pipelined
// (per-iter vmcnt(0) drain, full mem latency serialized per wave). Fix:
// __launch_bounds__(256,4) (128-VGPR budget) + 4x unroll with hoisted loads
// (8 independent 16B loads in flight) + pure-VALU bin update.

#define NBIN 16
#define THREADS 256
#define NBLOCKS 2048
#define UNROLL 4
#define WS_STRIDE 64   // spread 33 accumulators 256B apart (distinct L2 lines)

__global__ __launch_bounds__(THREADS, 4)   // 4 waves/EU -> <=128 VGPR, accums stay in VGPRs
void bll_pass(const float* __restrict__ outputs, const float* __restrict__ targets,
              float* __restrict__ ws, int n4) {
    // float32 values of np.arange(0.2, 1.0, 0.05) after f64->f32 cast.
    const float bins[NBIN] = {0.20f, 0.25f, 0.30f, 0.35f, 0.40f, 0.45f, 0.50f, 0.55f,
                              0.60f, 0.65f, 0.70f, 0.75f, 0.80f, 0.85f, 0.90f, 0.95f};

    float cs[NBIN];            // cumulative weighted-L1 sums (static idx -> VGPR)
    unsigned int cn[NBIN];     // cumulative counts (v_cmp + v_addc path)
    float ts = 0.0f;           // total L1 sum
    #pragma unroll
    for (int b = 0; b < NBIN; ++b) { cs[b] = 0.0f; cn[b] = 0u; }

    const float4* __restrict__ t4p = (const float4*)targets;
    const float4* __restrict__ o4p = (const float4*)outputs;
    const int stride = gridDim.x * THREADS;

#define PROC1(tq, oq)                                                        \
    {                                                                        \
        const float tv[4] = {tq.x, tq.y, tq.z, tq.w};                        \
        const float ov[4] = {oq.x, oq.y, oq.z, oq.w};                        \
        _Pragma("unroll")                                                    \
        for (int c = 0; c < 4; ++c) {                                        \
            const float tc = tv[c];                                          \
            const float l1 = fabsf(ov[c] - tc);                              \
            ts += l1;                                                        \
            _Pragma("unroll")                                                \
            for (int b = 0; b < NBIN; ++b) {                                 \
                const bool p = (tc >= bins[b]);                              \
                cs[b] += p ? l1 : 0.0f;                                      \
                cn[b] += (unsigned int)p;                                    \
            }                                                                \
        }                                                                    \
    }

    int i = blockIdx.x * THREADS + threadIdx.x;
    // Unrolled chunks: 8 independent 16B loads issued before any compute.
    for (; i + (UNROLL - 1) * stride < n4; i += UNROLL * stride) {
        const float4 t0 = t4p[i];
        const float4 t1 = t4p[i + stride];
        const float4 t2 = t4p[i + 2 * stride];
        const float4 t3 = t4p[i + 3 * stride];
        const float4 o0 = o4p[i];
        const float4 o1 = o4p[i + stride];
        const float4 o2 = o4p[i + 2 * stride];
        const float4 o3 = o4p[i + 3 * stride];
        PROC1(t0, o0) PROC1(t1, o1) PROC1(t2, o2) PROC1(t3, o3)
    }
    // Tail (empty for n4 = 2048*256*8 but kept generic).
    for (; i < n4; i += stride) {
        const float4 tq = t4p[i];
        const float4 oq = o4p[i];
        PROC1(tq, oq)
    }
#undef PROC1

    // ---- reduction: wave butterfly, then 4 waves via tiny LDS ----
    #pragma unroll
    for (int b = 0; b < NBIN; ++b) {
        #pragma unroll
        for (int off = 32; off; off >>= 1) cs[b] += __shfl_xor(cs[b], off);
    }
    #pragma unroll
    for (int b = 0; b < NBIN; ++b) {
        #pragma unroll
        for (int off = 32; off; off >>= 1) cn[b] += __shfl_xor((int)cn[b], off);
    }
    #pragma unroll
    for (int off = 32; off; off >>= 1) ts += __shfl_xor(ts, off);

    __shared__ float red[4][33];   // 4 waves x (16 cs + 16 cn + ts)
    const int lane = threadIdx.x & 63;
    const int wv   = threadIdx.x >> 6;
    if (lane == 0) {
        #pragma unroll
        for (int b = 0; b < NBIN; ++b) {
            red[wv][b]        = cs[b];
            red[wv][NBIN + b] = (float)cn[b];
        }
        red[wv][32] = ts;
    }
    __syncthreads();
    if (threadIdx.x < 33) {
        const float v = red[0][threadIdx.x] + red[1][threadIdx.x] +
                        red[2][threadIdx.x] + red[3][threadIdx.x];
        unsafeAtomicAdd(&ws[threadIdx.x * WS_STRIDE], v);
    }
}

// ws[s*WS_STRIDE]: s in [0,16) = cumS, [16,32) = cumN, 32 = totS
__global__ void bll_final(const float* __restrict__ ws, const float* __restrict__ counts,
                          float* __restrict__ out, float totN) {
    if (threadIdx.x == 0 && blockIdx.x == 0) {
        float cumS[NBIN + 1], cumN[NBIN + 1];
        #pragma unroll
        for (int b = 0; b < NBIN; ++b) {
            cumS[b] = ws[b * WS_STRIDE];
            cumN[b] = ws[(NBIN + b) * WS_STRIDE];
        }
        cumS[NBIN] = 0.0f;
        cumN[NBIN] = 0.0f;
        const float totS = ws[32 * WS_STRIDE];

        const float S_inv = totS - cumS[0];
        const float N_inv = totN - cumN[0];

        float Nb[NBIN], Sb[NBIN], newc[NBIN];
        float total = 0.0f;
        #pragma unroll
        for (int b = 0; b < NBIN; ++b) {
            Sb[b] = cumS[b] - cumS[b + 1];
            Nb[b] = cumN[b] - cumN[b + 1];
            newc[b] = 0.9f * counts[b] + 0.1f * Nb[b];   // EMA
            total += newc[b];
        }
        float num = S_inv;
        float den = N_inv;
        #pragma unroll
        for (int b = 0; b < NBIN; ++b) {
            const float wi = sqrtf(total / newc[b]);     // (1/freq)^0.5
            num += wi * Sb[b];
            den += wi * Nb[b];
        }
        out[0] = num / den;                              // * LOSS_WEIGHT (=1)
    }
}

extern "C" void kernel_launch(void* const* d_in, const int* in_sizes, int n_in,
                              void* d_out, int out_size, void* d_ws, size_t ws_size,
                              hipStream_t stream) {
    const float* outputs = (const float*)d_in[0];
    const float* targets = (const float*)d_in[1];
    const float* counts  = (const float*)d_in[2];
    float* out = (float*)d_out;
    float* ws  = (float*)d_ws;

    const int n  = in_sizes[0];   // 64*512*512 = 16,777,216 (divisible by 4)
    const int n4 = n >> 2;

    hipMemsetAsync(ws, 0, 33 * WS_STRIDE * sizeof(float), stream);
    bll_pass<<<NBLOCKS, THREADS, 0, stream>>>(outputs, targets, ws, n4);
    bll_final<<<1, 64, 0, stream>>>(ws, counts, out, (float)n);
}